// Round 14
// baseline (170.230 us; speedup 1.0000x reference)
//
#include <hip/hip_runtime.h>

typedef unsigned int uint;
typedef unsigned short ushort;
typedef unsigned long long ullong;
typedef __attribute__((ext_vector_type(8))) short short8;   // 8 bf16 = 4 VGPRs
typedef __attribute__((ext_vector_type(4))) float floatx4;  // MFMA C/D

#define N_NODES 50000
#define N_EDGES 1600000
#define DIM 128
#define LN_EPS 1e-10f

#define NB4 3125                 // quarter-buckets of 16 rows: 50000/16 EXACT
#define CAP4 704                 // mean 512, +8.5 sigma
#define EPB 6250                 // edges per scatter block (256*6250 = 1.6M exact)
#define SB 256                   // scatter blocks
#define CONVB 256                // grid-stride convert blocks fused into prep
#define CAPR 76                  // per-row agg list slots (mean 32, +7.8 sigma)

__device__ __forceinline__ uint f2bf(float x) {
    uint u = __float_as_uint(x);
    return (u + 0x7FFFu + ((u >> 16) & 1u)) >> 16;   // RNE to bf16
}

// ---------------------------------------------------------------------------
// prep (R32): R24 structure with bins = 16 rows (r>>4, 3125 bins) to feed
// the finer-grained agg.  To keep 2 blocks/CU despite the bigger tables,
// gbase is FOLDED into a delta table reusing cnt's LDS: after the scan,
// cnt[b] := gbase[b] - lbase[b], so phase D's slot is cnt[b] + j.
// LDS = 12.5(cnt) + 12.5(lbase) + 50(stageE) = 75 KB -> 2 blocks/CU.
// Phase A histogram atomicAdd return value = edge's rank within its bin;
// phase C places at lbase[b]+rank; phase D flushes in slot order ==
// destination order (full-line clustered perm writes).  Convert blocks
// (feat/W -> bf16) ride along grid-stride, no LDS use.
// ---------------------------------------------------------------------------
__global__ __launch_bounds__(1024, 8) void prep(
    const float* __restrict__ feat, const float* __restrict__ W,
    const int* __restrict__ rows, const int* __restrict__ cols,
    const float* __restrict__ vals, int* __restrict__ gcnt,
    int2* __restrict__ perm, uint* __restrict__ featb_u,
    ushort* __restrict__ wbf)
{
    __shared__ int  cnt[NB4];           // 12.5 KB (becomes delta after scan)
    __shared__ int  lbase[NB4];         // 12.5 KB
    __shared__ int  csum[64];
    __shared__ int2 stageE[EPB];        // 50 KB   (total 75 KB -> 2 blocks/CU)
    const int bx = blockIdx.x;
    const int t  = threadIdx.x;

    if (bx >= SB) {                      // ---- fused convert (no LDS use) ----
        const int cb = bx - SB;
        const int stride = CONVB * 1024;
        for (int i = cb * 1024 + t; i < N_NODES * DIM / 4; i += stride) {
            float4 v = ((const float4*)feat)[i];
            ((uint2*)featb_u)[i] = make_uint2(
                f2bf(v.x) | (f2bf(v.y) << 16),
                f2bf(v.z) | (f2bf(v.w) << 16));
        }
        for (int i = cb * 1024 + t; i < DIM * DIM / 4; i += stride) {
            float4 v = ((const float4*)W)[i];
            ushort4 o;
            o.x = (ushort)f2bf(v.x); o.y = (ushort)f2bf(v.y);
            o.z = (ushort)f2bf(v.z); o.w = (ushort)f2bf(v.w);
            ((ushort4*)wbf)[i] = o;
        }
        return;
    }

    // ---- phase A: rows -> rank-within-bin, stashed in registers ----
    for (int i = t; i < NB4; i += 1024) cnt[i] = 0;
    __syncthreads();
    const int base = bx * EPB;
    uint pk[7];                          // EPB = 6*1024 + 106
    #pragma unroll
    for (int i = 0; i < 7; ++i) {
        int k = i * 1024 + t;
        if (k < EPB) {
            int r = rows[base + k];
            int rank = atomicAdd(&cnt[r >> 4], 1);  // rank < 6250 (13 bits)
            pk[i] = ((uint)rank << 16) | (uint)r;   // r < 50000 (16 bits)
        }
    }
    __syncthreads();

    // ---- phase B: global reservation (line-rotated, gbase in regs) ----
    const int rot = (bx * 16) % NB4;                 // 64 B line offset/block
    int gsav[4];
    #pragma unroll
    for (int s = 0; s < 4; ++s) {
        int i = t + s * 1024;
        if (i < NB4) {
            int ii = i + rot; if (ii >= NB4) ii -= NB4;
            int c = cnt[ii];
            gsav[s] = c ? atomicAdd(&gcnt[ii], c) : 0;
        }
    }
    // LDS exclusive scan (64 x 49) -> lbase
    if (t < 64) {
        int s = 0;
        for (int j = 0; j < 49; ++j) {
            int idx = t * 49 + j;
            if (idx < NB4) s += cnt[idx];
        }
        csum[t] = s;
    }
    __syncthreads();
    if (t == 0) {
        int s = 0;
        for (int i = 0; i < 64; ++i) { int c = csum[i]; csum[i] = s; s += c; }
    }
    __syncthreads();
    if (t < 64) {
        int run = csum[t];
        for (int j = 0; j < 49; ++j) {
            int idx = t * 49 + j;
            if (idx < NB4) { lbase[idx] = run; run += cnt[idx]; }
        }
    }
    __syncthreads();

    // ---- fold: cnt[b] := gbase[b] - lbase[b]  (phase D slot = cnt[b]+j) ----
    #pragma unroll
    for (int s = 0; s < 4; ++s) {
        int i = t + s * 1024;
        if (i < NB4) {
            int ii = i + rot; if (ii >= NB4) ii -= NB4;
            cnt[ii] = gsav[s] - lbase[ii];
        }
    }
    __syncthreads();

    // ---- phase C: stage grouped by bin -- atomic-free placement ----
    // pack: col (16b) | local row r&15 (4b, bits 16-19) | bin (12b, bits 20-31)
    #pragma unroll
    for (int i = 0; i < 7; ++i) {
        int k = i * 1024 + t;
        if (k < EPB) {
            uint s = pk[i];
            int r = (int)(s & 0xFFFFu);
            int rank = (int)(s >> 16);
            int b = r >> 4;
            int pos = lbase[b] + rank;
            stageE[pos] = make_int2(
                (uint)cols[base + k] | ((uint)(r & 15) << 16) | ((uint)b << 20),
                __float_as_int(vals[base + k]));
        }
    }
    __syncthreads();

    // ---- phase D: clustered flush (slot order == destination order) ----
    for (int j = t; j < EPB; j += 1024) {
        int2 p = stageE[j];
        uint b = ((uint)p.x) >> 20;
        int pos = cnt[b] + j;            // = gbase[b] + (j - lbase[b])
        if (pos < CAP4)                  // statistically impossible; safety
            perm[(size_t)b * CAP4 + pos] = p;       // agg masks b bits
    }
}

// ---------------------------------------------------------------------------
// agg_fused (R32): 16-row blocks -- 3125 x 256 thr (4 waves), 50000=3125*16
// EXACT (tail check gone).  Same 32 waves/CU as R31 (8 blocks x 4 waves vs
// 4 x 8) but HALF the barrier-coupled granularity: phases half as long,
// retire/launch stream twice as fine, 8 independent blocks interleave
// gather/MFMA phases per CU.  Evidence: bigger/longer blocks lose (R19/R26);
// 64->32 rows won (R22); this tests 32->16.  NT hints kept (R31: -2.4us).
// P4 reshapes to 1 M-tile x 2 N-tiles per wave (same chip-wide MFMA count).
// P1 BYTE offsets (col<<8); P2 12-deep gather; P3 LDS stride 136; P5 LN.
// ---------------------------------------------------------------------------
__global__ __launch_bounds__(256, 8) void agg_fused(
    const int2* __restrict__ perm, const int* __restrict__ gcnt,
    const ushort* __restrict__ featb, const ushort* __restrict__ wbf,
    const float* __restrict__ bias, const float* __restrict__ scale,
    const float* __restrict__ offset, float* __restrict__ out)
{
    __shared__ int2 lists[16 * CAPR];    // 9728 B union:
    ushort* rowsbuf = (ushort*)lists;    //   P3/P4: 16 x 136 bf16 (4352 B)
    float*  Cbuf    = (float*)lists;     //   P5:    16 x 132 fp32 (8448 B)
    __shared__ int  lcnt[16];

    const int t = threadIdx.x;

    // bijective XCD-chunked swizzle: each XCD gets a contiguous bin range
    const int q = NB4 >> 3, rr = NB4 & 7;
    const int xcd = blockIdx.x & 7, within = blockIdx.x >> 3;
    const int hb = (xcd < rr ? xcd * (q + 1) : rr * (q + 1) + (xcd - rr) * q) + within;

    if (t < 16) lcnt[t] = 0;
    __syncthreads();

    int n = gcnt[hb];
    if (n > CAP4) n = CAP4;
    const int2* pb = perm + (size_t)hb * CAP4;

    // ---- P1: compaction; perm is single-use -> non-temporal load ----
    for (int e = t; e < n; e += 256) {
        ullong pv = __builtin_nontemporal_load((const ullong*)&pb[e]);
        int px = (int)(uint)pv;
        int py = (int)(uint)(pv >> 32);
        int rl = (px >> 16) & 15;
        int pos = atomicAdd(&lcnt[rl], 1);
        if (pos < CAPR)
            lists[rl * CAPR + pos] = make_int2((px & 0xFFFF) << 8, py);
    }
    __syncthreads();

    const int lane = t & 63;
    const int wid  = t >> 6;        // 0..3
    const int rb   = wid * 4;       // this wave's first local row (0..12)
    const char* fbase = (const char*)featb;
    const uint  lane4 = (uint)lane << 2;

    // ---- P2: gather + accumulate (ax = elem 2*lane, ay = elem 2*lane+1) ----
    float ax[4], ay[4];
    #pragma unroll
    for (int j = 0; j < 4; ++j) {
        int rl = rb + j;
        int cnt = lcnt[rl];
        if (cnt > CAPR) cnt = CAPR;
        const int2* L = &lists[rl * CAPR];
        float sx = 0.f, sy = 0.f;
        int e = 0;
        for (; e + 11 < cnt; e += 12) {           // 12 outstanding gathers
            int4 q6[6]; uint g[12];
            #pragma unroll
            for (int k = 0; k < 6; ++k) q6[k] = *(const int4*)&L[e + 2 * k];
            #pragma unroll
            for (int k = 0; k < 6; ++k) {
                g[2*k]   = *(const uint*)(fbase + ((uint)q6[k].x + lane4));
                g[2*k+1] = *(const uint*)(fbase + ((uint)q6[k].z + lane4));
            }
            #pragma unroll
            for (int k = 0; k < 6; ++k) {
                float v0 = __int_as_float(q6[k].y);
                float v1 = __int_as_float(q6[k].w);
                sx = fmaf(v0, __uint_as_float(g[2*k] << 16), sx);
                sy = fmaf(v0, __uint_as_float(g[2*k] & 0xFFFF0000u), sy);
                sx = fmaf(v1, __uint_as_float(g[2*k+1] << 16), sx);
                sy = fmaf(v1, __uint_as_float(g[2*k+1] & 0xFFFF0000u), sy);
            }
        }
        for (; e + 3 < cnt; e += 4) {
            int4 q2[2]; uint g[4];
            #pragma unroll
            for (int k = 0; k < 2; ++k) q2[k] = *(const int4*)&L[e + 2 * k];
            #pragma unroll
            for (int k = 0; k < 2; ++k) {
                g[2*k]   = *(const uint*)(fbase + ((uint)q2[k].x + lane4));
                g[2*k+1] = *(const uint*)(fbase + ((uint)q2[k].z + lane4));
            }
            #pragma unroll
            for (int k = 0; k < 2; ++k) {
                float v0 = __int_as_float(q2[k].y);
                float v1 = __int_as_float(q2[k].w);
                sx = fmaf(v0, __uint_as_float(g[2*k] << 16), sx);
                sy = fmaf(v0, __uint_as_float(g[2*k] & 0xFFFF0000u), sy);
                sx = fmaf(v1, __uint_as_float(g[2*k+1] << 16), sx);
                sy = fmaf(v1, __uint_as_float(g[2*k+1] & 0xFFFF0000u), sy);
            }
        }
        for (; e < cnt; ++e) {
            int2 p = L[e];
            uint g = *(const uint*)(fbase + ((uint)p.x + lane4));
            float v = __int_as_float(p.y);
            sx = fmaf(v, __uint_as_float(g << 16), sx);
            sy = fmaf(v, __uint_as_float(g & 0xFFFF0000u), sy);
        }
        ax[j] = sx; ay[j] = sy;
    }
    __syncthreads();               // lists dead

    // ---- P3: rows -> LDS bf16 (true element order), stride 136 ushorts ----
    #pragma unroll
    for (int j = 0; j < 4; ++j) {
        uint pkd = f2bf(ax[j]) | (f2bf(ay[j]) << 16);
        *(uint*)&rowsbuf[(rb + j) * 136 + 2 * lane] = pkd;
    }
    __syncthreads();

    // ---- P4: MFMA GEMM, 1 M-tile x 2 N-tiles per wave ----
    const int l15  = lane & 15;
    const int quad = lane >> 4;
    const int n0a  = wid * 32 + l15;       // this wave's first N-column
    const int n0b  = n0a + 16;             // second N-tile
    const float bba = bias[n0a], bbb = bias[n0b];

    floatx4 acca = {0.f, 0.f, 0.f, 0.f};
    floatx4 accb = {0.f, 0.f, 0.f, 0.f};
    #pragma unroll
    for (int kt = 0; kt < 4; ++kt) {
        int k0 = kt * 32 + quad * 8;
        short8 af  = *(const short8*)&rowsbuf[l15 * 136 + k0];
        short8 bfa = *(const short8*)&wbf[n0a * DIM + k0];   // B[k][n]=W[n][k]
        short8 bfb = *(const short8*)&wbf[n0b * DIM + k0];
        acca = __builtin_amdgcn_mfma_f32_16x16x32_bf16(af, bfa, acca, 0, 0, 0);
        accb = __builtin_amdgcn_mfma_f32_16x16x32_bf16(af, bfb, accb, 0, 0, 0);
    }
    __syncthreads();               // rowsbuf dead

    // C/D layout: lane holds D[m=quad*4+r][n=l15] -> stage to Cbuf (+bias)
    #pragma unroll
    for (int r = 0; r < 4; ++r) {
        int m = quad * 4 + r;
        Cbuf[m * 132 + n0a] = acca[r] + bba;
        Cbuf[m * 132 + n0b] = accb[r] + bbb;
    }
    __syncthreads();

    // ---- P5: ReLU + LN + scale/offset -> out (4 rows per wave, NT) ----
    const float sc0 = scale[lane],  sc1 = scale[lane + 64];
    const float of0 = offset[lane], of1 = offset[lane + 64];

    #pragma unroll
    for (int j = 0; j < 4; ++j) {
        int rl = rb + j;
        int r  = hb * 16 + rl;                            // exact: no tail
        float A0 = fmaxf(Cbuf[rl * 132 + lane],      0.0f);
        float A1 = fmaxf(Cbuf[rl * 132 + lane + 64], 0.0f);

        float s = A0 + A1;
        #pragma unroll
        for (int off = 32; off >= 1; off >>= 1) s += __shfl_xor(s, off, 64);
        float mean = s * (1.0f / 128.0f);

        float d0 = A0 - mean, d1 = A1 - mean;
        float q2 = d0 * d0 + d1 * d1;
        #pragma unroll
        for (int off = 32; off >= 1; off >>= 1) q2 += __shfl_xor(q2, off, 64);
        float rstd = rsqrtf(q2 * (1.0f / 128.0f) + LN_EPS);

        size_t rowp = (size_t)r * DIM;
        __builtin_nontemporal_store(d0 * sc0 * rstd + of0, &out[rowp + lane]);
        __builtin_nontemporal_store(d1 * sc1 * rstd + of1, &out[rowp + lane + 64]);
    }
}

extern "C" void kernel_launch(void* const* d_in, const int* in_sizes, int n_in,
                              void* d_out, int out_size, void* d_ws, size_t ws_size,
                              hipStream_t stream) {
    const float* feat_in = (const float*)d_in[0];
    const int*   rows    = (const int*)d_in[1];
    const int*   cols    = (const int*)d_in[2];
    const float* vals    = (const float*)d_in[3];
    const float* W       = (const float*)d_in[4];
    const float* bias    = (const float*)d_in[5];
    const float* scale   = (const float*)d_in[6];
    const float* offset  = (const float*)d_in[7];
    float* out = (float*)d_out;

    // ---- workspace layout ----
    char* p = (char*)d_ws;
    int2* perm = (int2*)p;                 p += (size_t)NB4 * CAP4 * 8;        // 17.6 MB
    ushort* featb = (ushort*)p;            p += (size_t)N_NODES * DIM * 2;     // 12.8 MB
    ushort* wbf = (ushort*)p;              p += DIM * DIM * 2;                 // 32 KB
    int*  gcnt = (int*)p;                  p += (size_t)(NB4 + 64) * 4;        // 12.8 KB

    hipMemsetAsync(gcnt, 0, (size_t)NB4 * sizeof(int), stream);

    prep<<<SB + CONVB, 1024, 0, stream>>>(feat_in, W, rows, cols, vals,
                                          gcnt, perm, (uint*)featb, wbf);
    agg_fused<<<NB4, 256, 0, stream>>>(perm, gcnt, featb, wbf,
                                       bias, scale, offset, out);
}

// Round 16
// 164.816 us; speedup vs baseline: 1.0328x; 1.0328x over previous
//
#include <hip/hip_runtime.h>

typedef unsigned int uint;
typedef unsigned short ushort;
typedef unsigned long long ullong;
typedef __attribute__((ext_vector_type(8))) short short8;   // 8 bf16 = 4 VGPRs
typedef __attribute__((ext_vector_type(4))) float floatx4;  // MFMA C/D
typedef __attribute__((ext_vector_type(4))) float floatv4;  // NT-loadable f32x4

#define N_NODES 50000
#define N_EDGES 1600000
#define DIM 128
#define LN_EPS 1e-10f

#define NB2 1564                 // half-buckets of 32 rows: ceil(50000/32)
#define CAP2 1280                // mean 1024, +8 sigma
#define EPB 6250                 // edges per scatter block (256*6250 = 1.6M exact)
#define SB 256                   // scatter blocks
#define CONVB 256                // grid-stride convert blocks fused into prep
#define CAPR 76                  // per-row agg list slots (mean 32, +7.8 sigma)

__device__ __forceinline__ uint f2bf(float x) {
    uint u = __float_as_uint(x);
    return (u + 0x7FFFu + ((u >> 16) & 1u)) >> 16;   // RNE to bf16
}

// ---------------------------------------------------------------------------
// prep (R34 = R33 with the NT-load type fixed: __builtin_nontemporal_load
// needs a clang ext_vector, not HIP_vector_type).  NT loads on the four
// SINGLE-USE input streams: feat (25.6 MB, convert), rows (6.4 MB, phase A),
// cols/vals (12.8 MB, phase C).  All read exactly once; without hints they
// churn L2 while convert concurrently writes featb -- the array agg re-reads
// 410 MB-logical from.  Same mechanism as R31's agg win, producer-side.
// Writes stay normal (featb/perm are consumed by agg).  32-row bins
// (granularity curve mapped R32: 64->65.5, 32->58.0 optimum, 16->59.4).
// Fused scatter + grid-stride convert, register edge stash, 69 KB LDS ->
// 2 blocks/CU, line-rotated phase-B reservation atomics.
// ---------------------------------------------------------------------------
__global__ __launch_bounds__(1024, 8) void prep(
    const float* __restrict__ feat, const float* __restrict__ W,
    const int* __restrict__ rows, const int* __restrict__ cols,
    const float* __restrict__ vals, int* __restrict__ gcnt,
    int2* __restrict__ perm, uint* __restrict__ featb_u,
    ushort* __restrict__ wbf)
{
    __shared__ int  cnt[NB2];           // 6.3 KB
    __shared__ int  gbase[NB2];         // 6.3 KB
    __shared__ int  lbase[NB2];         // 6.3 KB
    __shared__ int  csum[64];
    __shared__ int2 stageE[EPB];        // 50 KB   (total 69 KB -> 2 blocks/CU)
    const int bx = blockIdx.x;
    const int t  = threadIdx.x;

    if (bx >= SB) {                      // ---- fused convert (no LDS use) ----
        const int cb = bx - SB;
        const int stride = CONVB * 1024;
        for (int i = cb * 1024 + t; i < N_NODES * DIM / 4; i += stride) {
            floatv4 v = __builtin_nontemporal_load(&((const floatv4*)feat)[i]);
            ((uint2*)featb_u)[i] = make_uint2(
                f2bf(v.x) | (f2bf(v.y) << 16),
                f2bf(v.z) | (f2bf(v.w) << 16));
        }
        for (int i = cb * 1024 + t; i < DIM * DIM / 4; i += stride) {
            floatv4 v = ((const floatv4*)W)[i];
            ushort4 o;
            o.x = (ushort)f2bf(v.x); o.y = (ushort)f2bf(v.y);
            o.z = (ushort)f2bf(v.z); o.w = (ushort)f2bf(v.w);
            ((ushort4*)wbf)[i] = o;
        }
        return;
    }

    // ---- phase A: rows -> rank-within-bin, stashed in registers ----
    for (int i = t; i < NB2; i += 1024) cnt[i] = 0;
    __syncthreads();
    const int base = bx * EPB;
    uint pk[7];                          // EPB = 6*1024 + 106
    #pragma unroll
    for (int i = 0; i < 7; ++i) {
        int k = i * 1024 + t;
        if (k < EPB) {
            int r = __builtin_nontemporal_load(&rows[base + k]);
            int rank = atomicAdd(&cnt[r >> 5], 1);  // rank < 6250 (13 bits)
            pk[i] = ((uint)rank << 16) | (uint)r;   // r < 50000 (16 bits)
        }
    }
    __syncthreads();

    // ---- phase B: global reservation (line-rotated) + LDS scan (64x25) ----
    {
        const int rot = (bx * 16) % NB2;             // 64 B line offset/block
        for (int i = t; i < NB2; i += 1024) {
            int ii = i + rot; if (ii >= NB2) ii -= NB2;
            int c = cnt[ii];
            gbase[ii] = c ? atomicAdd(&gcnt[ii], c) : 0;
        }
    }
    if (t < 64) {
        int s = 0;
        for (int j = 0; j < 25; ++j) {
            int idx = t * 25 + j;
            if (idx < NB2) s += cnt[idx];
        }
        csum[t] = s;
    }
    __syncthreads();
    if (t == 0) {
        int s = 0;
        for (int i = 0; i < 64; ++i) { int c = csum[i]; csum[i] = s; s += c; }
    }
    __syncthreads();
    if (t < 64) {
        int run = csum[t];
        for (int j = 0; j < 25; ++j) {
            int idx = t * 25 + j;
            if (idx < NB2) { lbase[idx] = run; run += cnt[idx]; }
        }
    }
    __syncthreads();

    // ---- phase C: stage grouped by bin -- atomic-free placement ----
    // pack: col (16b) | local row r&31 (5b, bits 16-20) | bin (11b, bits 21-31)
    #pragma unroll
    for (int i = 0; i < 7; ++i) {
        int k = i * 1024 + t;
        if (k < EPB) {
            uint s = pk[i];
            int r = (int)(s & 0xFFFFu);
            int rank = (int)(s >> 16);
            int b = r >> 5;
            int pos = lbase[b] + rank;
            int c = __builtin_nontemporal_load(&cols[base + k]);
            float v = __builtin_nontemporal_load(&vals[base + k]);
            stageE[pos] = make_int2(
                (uint)c | ((uint)(r & 31) << 16) | ((uint)b << 21),
                __float_as_int(v));
        }
    }
    __syncthreads();

    // ---- phase D: clustered flush (slot order == destination order) ----
    for (int j = t; j < EPB; j += 1024) {
        int2 p = stageE[j];
        uint b = ((uint)p.x) >> 21;
        int pos = gbase[b] + (j - lbase[b]);
        if (pos < CAP2)                 // statistically impossible; safety
            perm[(size_t)b * CAP2 + pos] = p;       // agg masks b bits
    }
}

// ---------------------------------------------------------------------------
// agg_fused (R34 = R31 verbatim -- the measured-best agg: 58.0us, FETCH
// 144.9MB).  NT load on single-use perm (P1), NT store on write-once out
// (P5) -- R31's win (-2.4us).  32-row blocks, 12-deep P2 gather (compiler
// holds ~8 real outstanding loads regardless of deeper source chunking --
// R28/R29/R30 all regressed), (512,8) bounds, XCD swizzle, stride-136 LDS.
// ---------------------------------------------------------------------------
__global__ __launch_bounds__(512, 8) void agg_fused(
    const int2* __restrict__ perm, const int* __restrict__ gcnt,
    const ushort* __restrict__ featb, const ushort* __restrict__ wbf,
    const float* __restrict__ bias, const float* __restrict__ scale,
    const float* __restrict__ offset, float* __restrict__ out)
{
    __shared__ int2 lists[32 * CAPR];    // 19456 B union:
    ushort* rowsbuf = (ushort*)lists;    //   P3/P4: 32 x 136 bf16 (8704 B)
    float*  Cbuf    = (float*)lists;     //   P5:    32 x 132 fp32 (16896 B)
    __shared__ int  lcnt[32];

    const int t = threadIdx.x;

    // bijective XCD-chunked swizzle: each XCD gets a contiguous bin range
    const int q = NB2 >> 3, rr = NB2 & 7;
    const int xcd = blockIdx.x & 7, within = blockIdx.x >> 3;
    const int hb = (xcd < rr ? xcd * (q + 1) : rr * (q + 1) + (xcd - rr) * q) + within;

    if (t < 32) lcnt[t] = 0;
    __syncthreads();

    int n = gcnt[hb];
    if (n > CAP2) n = CAP2;
    const int2* pb = perm + (size_t)hb * CAP2;

    // ---- P1: compaction; perm is single-use -> non-temporal load ----
    for (int e = t; e < n; e += 512) {
        ullong pv = __builtin_nontemporal_load((const ullong*)&pb[e]);
        int px = (int)(uint)pv;
        int py = (int)(uint)(pv >> 32);
        int rl = (px >> 16) & 31;
        int pos = atomicAdd(&lcnt[rl], 1);
        if (pos < CAPR)
            lists[rl * CAPR + pos] = make_int2((px & 0xFFFF) << 8, py);
    }
    __syncthreads();

    const int lane = t & 63;
    const int wid  = t >> 6;        // 0..7
    const int rb   = wid * 4;       // this wave's first local row
    const char* fbase = (const char*)featb;
    const uint  lane4 = (uint)lane << 2;

    // ---- P2: gather + accumulate (ax = elem 2*lane, ay = elem 2*lane+1) ----
    float ax[4], ay[4];
    #pragma unroll
    for (int j = 0; j < 4; ++j) {
        int rl = rb + j;
        int cnt = lcnt[rl];
        if (cnt > CAPR) cnt = CAPR;
        const int2* L = &lists[rl * CAPR];
        float sx = 0.f, sy = 0.f;
        int e = 0;
        for (; e + 11 < cnt; e += 12) {           // 12 outstanding gathers
            int4 q6[6]; uint g[12];
            #pragma unroll
            for (int k = 0; k < 6; ++k) q6[k] = *(const int4*)&L[e + 2 * k];
            #pragma unroll
            for (int k = 0; k < 6; ++k) {
                g[2*k]   = *(const uint*)(fbase + ((uint)q6[k].x + lane4));
                g[2*k+1] = *(const uint*)(fbase + ((uint)q6[k].z + lane4));
            }
            #pragma unroll
            for (int k = 0; k < 6; ++k) {
                float v0 = __int_as_float(q6[k].y);
                float v1 = __int_as_float(q6[k].w);
                sx = fmaf(v0, __uint_as_float(g[2*k] << 16), sx);
                sy = fmaf(v0, __uint_as_float(g[2*k] & 0xFFFF0000u), sy);
                sx = fmaf(v1, __uint_as_float(g[2*k+1] << 16), sx);
                sy = fmaf(v1, __uint_as_float(g[2*k+1] & 0xFFFF0000u), sy);
            }
        }
        for (; e + 3 < cnt; e += 4) {
            int4 q2[2]; uint g[4];
            #pragma unroll
            for (int k = 0; k < 2; ++k) q2[k] = *(const int4*)&L[e + 2 * k];
            #pragma unroll
            for (int k = 0; k < 2; ++k) {
                g[2*k]   = *(const uint*)(fbase + ((uint)q2[k].x + lane4));
                g[2*k+1] = *(const uint*)(fbase + ((uint)q2[k].z + lane4));
            }
            #pragma unroll
            for (int k = 0; k < 2; ++k) {
                float v0 = __int_as_float(q2[k].y);
                float v1 = __int_as_float(q2[k].w);
                sx = fmaf(v0, __uint_as_float(g[2*k] << 16), sx);
                sy = fmaf(v0, __uint_as_float(g[2*k] & 0xFFFF0000u), sy);
                sx = fmaf(v1, __uint_as_float(g[2*k+1] << 16), sx);
                sy = fmaf(v1, __uint_as_float(g[2*k+1] & 0xFFFF0000u), sy);
            }
        }
        for (; e < cnt; ++e) {
            int2 p = L[e];
            uint g = *(const uint*)(fbase + ((uint)p.x + lane4));
            float v = __int_as_float(p.y);
            sx = fmaf(v, __uint_as_float(g << 16), sx);
            sy = fmaf(v, __uint_as_float(g & 0xFFFF0000u), sy);
        }
        ax[j] = sx; ay[j] = sy;
    }
    __syncthreads();               // lists dead

    // ---- P3: rows -> LDS bf16 (true element order), stride 136 ushorts ----
    #pragma unroll
    for (int j = 0; j < 4; ++j) {
        uint pkd = f2bf(ax[j]) | (f2bf(ay[j]) << 16);
        *(uint*)&rowsbuf[(rb + j) * 136 + 2 * lane] = pkd;
    }
    __syncthreads();

    // ---- P4: MFMA GEMM.  D[m][n] = sum_k A[m][k] * W[n][k] ----
    const int l15  = lane & 15;
    const int quad = lane >> 4;
    const int n0   = wid * 16 + l15;       // this wave's N-column
    const float bb = bias[n0];

    floatx4 acc0 = {0.f, 0.f, 0.f, 0.f};   // m-tile 0 (rows 0..15)
    floatx4 acc1 = {0.f, 0.f, 0.f, 0.f};   // m-tile 1 (rows 16..31)
    #pragma unroll
    for (int kt = 0; kt < 4; ++kt) {
        int k0 = kt * 32 + quad * 8;
        short8 af0 = *(const short8*)&rowsbuf[l15 * 136 + k0];
        short8 af1 = *(const short8*)&rowsbuf[(l15 + 16) * 136 + k0];
        short8 bf  = *(const short8*)&wbf[n0 * DIM + k0];   // B[k][n]=W[n][k]
        acc0 = __builtin_amdgcn_mfma_f32_16x16x32_bf16(af0, bf, acc0, 0, 0, 0);
        acc1 = __builtin_amdgcn_mfma_f32_16x16x32_bf16(af1, bf, acc1, 0, 0, 0);
    }
    __syncthreads();               // rowsbuf dead

    // C/D layout: lane holds D[m=quad*4+r][n=l15] -> stage to Cbuf (+bias)
    #pragma unroll
    for (int r = 0; r < 4; ++r) {
        int m = quad * 4 + r;
        Cbuf[m * 132 + n0]        = acc0[r] + bb;
        Cbuf[(m + 16) * 132 + n0] = acc1[r] + bb;
    }
    __syncthreads();

    // ---- P5: ReLU + LN + scale/offset -> out (write-once: NT stores) ----
    const float sc0 = scale[lane],  sc1 = scale[lane + 64];
    const float of0 = offset[lane], of1 = offset[lane + 64];

    #pragma unroll
    for (int j = 0; j < 4; ++j) {
        int rl = rb + j;
        int r  = hb * 32 + rl;
        if (r >= N_NODES) continue;                       // wave-uniform
        float A0 = fmaxf(Cbuf[rl * 132 + lane],      0.0f);
        float A1 = fmaxf(Cbuf[rl * 132 + lane + 64], 0.0f);

        float s = A0 + A1;
        #pragma unroll
        for (int off = 32; off >= 1; off >>= 1) s += __shfl_xor(s, off, 64);
        float mean = s * (1.0f / 128.0f);

        float d0 = A0 - mean, d1 = A1 - mean;
        float q2 = d0 * d0 + d1 * d1;
        #pragma unroll
        for (int off = 32; off >= 1; off >>= 1) q2 += __shfl_xor(q2, off, 64);
        float rstd = rsqrtf(q2 * (1.0f / 128.0f) + LN_EPS);

        size_t rowp = (size_t)r * DIM;
        __builtin_nontemporal_store(d0 * sc0 * rstd + of0, &out[rowp + lane]);
        __builtin_nontemporal_store(d1 * sc1 * rstd + of1, &out[rowp + lane + 64]);
    }
}

extern "C" void kernel_launch(void* const* d_in, const int* in_sizes, int n_in,
                              void* d_out, int out_size, void* d_ws, size_t ws_size,
                              hipStream_t stream) {
    const float* feat_in = (const float*)d_in[0];
    const int*   rows    = (const int*)d_in[1];
    const int*   cols    = (const int*)d_in[2];
    const float* vals    = (const float*)d_in[3];
    const float* W       = (const float*)d_in[4];
    const float* bias    = (const float*)d_in[5];
    const float* scale   = (const float*)d_in[6];
    const float* offset  = (const float*)d_in[7];
    float* out = (float*)d_out;

    // ---- workspace layout ----
    char* p = (char*)d_ws;
    int2* perm = (int2*)p;                 p += (size_t)NB2 * CAP2 * 8;        // 16.0 MB
    ushort* featb = (ushort*)p;            p += (size_t)N_NODES * DIM * 2;     // 12.8 MB
    ushort* wbf = (ushort*)p;              p += DIM * DIM * 2;                 // 32 KB
    int*  gcnt = (int*)p;                  p += (size_t)(NB2 + 64) * 4;        // 6.4 KB

    (void)hipMemsetAsync(gcnt, 0, (size_t)NB2 * sizeof(int), stream);

    prep<<<SB + CONVB, 1024, 0, stream>>>(feat_in, W, rows, cols, vals,
                                          gcnt, perm, (uint*)featb, wbf);
    agg_fused<<<NB2, 512, 0, stream>>>(perm, gcnt, featb, wbf,
                                       bias, scale, offset, out);
}